// Round 1
// 372.357 us; speedup vs baseline: 1.1002x; 1.1002x over previous
//
#include <hip/hip_runtime.h>
#include <hip/hip_bf16.h>

#define B_    32
#define C_    512
#define S_    1024
#define G_    32
#define CPG_  16
#define C3_   1536
#define EPS_  1e-5f
#define SCALE_ 0.044194173824159216f   // 1/sqrt(512), folded into K during qkv epilogue

typedef __attribute__((ext_vector_type(4))) float  floatx4;
typedef __attribute__((ext_vector_type(8))) __bf16 bf16x8;

__device__ __forceinline__ float bf2f(unsigned short u) {
    union { unsigned int i; float f; } v; v.i = ((unsigned int)u) << 16; return v.f;
}
__device__ __forceinline__ unsigned short f2bf(float f) {
    union { float f; unsigned int i; } v; v.f = f;
    unsigned int r = v.i + 0x7fffu + ((v.i >> 16) & 1u);
    return (unsigned short)(r >> 16);
}

// direct global->LDS DMA, 16 bytes per lane. LDS dest = wave-uniform base + lane*16.
__device__ __forceinline__ void gl16(const unsigned short* g, unsigned short* l) {
    __builtin_amdgcn_global_load_lds(
        (const __attribute__((address_space(1))) unsigned int*)g,
        (__attribute__((address_space(3))) unsigned int*)l, 16, 0, 0);
}

// ---------------- group-norm stats ----------------
__global__ __launch_bounds__(256) void gn_stats(const float* __restrict__ x,
                                                float2* __restrict__ stats) {
    const size_t base = (size_t)blockIdx.x * (CPG_ * S_);
    const float4* xp = (const float4*)(x + base);
    float s = 0.f, ss = 0.f;
    for (int i = threadIdx.x; i < (CPG_ * S_) / 4; i += 256) {
        float4 v = xp[i];
        s  += v.x + v.y + v.z + v.w;
        ss += v.x * v.x + v.y * v.y + v.z * v.z + v.w * v.w;
    }
    #pragma unroll
    for (int o = 32; o; o >>= 1) { s += __shfl_down(s, o); ss += __shfl_down(ss, o); }
    __shared__ float a1[4], a2[4];
    const int wid = threadIdx.x >> 6, lane = threadIdx.x & 63;
    if (lane == 0) { a1[wid] = s; a2[wid] = ss; }
    __syncthreads();
    if (threadIdx.x == 0) {
        float S  = a1[0] + a1[1] + a1[2] + a1[3];
        float SS = a2[0] + a2[1] + a2[2] + a2[3];
        float mean = S * (1.f / 16384.f);
        float var  = SS * (1.f / 16384.f) - mean * mean;
        stats[blockIdx.x] = make_float2(mean, rsqrtf(var + EPS_));
    }
}

// ---------------- fp32 -> bf16 convert ----------------
__global__ __launch_bounds__(256) void cast_bf16(const float* __restrict__ src,
                                                 unsigned short* __restrict__ dst) {
    int i = (blockIdx.x * 256 + threadIdx.x) * 4;
    float4 v = *(const float4*)(src + i);
    ushort4 o; o.x = f2bf(v.x); o.y = f2bf(v.y); o.z = f2bf(v.z); o.w = f2bf(v.w);
    *(ushort4*)(dst + i) = o;
}

// ---------------- normalized x, transposed to [b][s][c], bf16 ----------------
__global__ __launch_bounds__(256) void xnt_kernel(const float* __restrict__ x,
                                                  const float* __restrict__ gamma,
                                                  const float* __restrict__ beta,
                                                  const float2* __restrict__ stats,
                                                  unsigned short* __restrict__ xnt) {
    const int b = blockIdx.z, c0 = blockIdx.y * 64, s0 = blockIdx.x * 64;
    __shared__ float tile[64][65];
    const float* xb = x + (size_t)b * (C_ * S_);
    const int t = threadIdx.x, tr = t >> 4, tc4 = (t & 15) * 4;
    #pragma unroll
    for (int i = 0; i < 4; i++) {
        int r = tr + i * 16;
        int c = c0 + r;
        float2 mv = stats[b * G_ + (c >> 4)];
        float a  = mv.y * gamma[c];
        float bb = beta[c] - mv.x * a;
        float4 v = *(const float4*)(xb + (size_t)c * S_ + s0 + tc4);
        tile[r][tc4 + 0] = a * v.x + bb;
        tile[r][tc4 + 1] = a * v.y + bb;
        tile[r][tc4 + 2] = a * v.z + bb;
        tile[r][tc4 + 3] = a * v.w + bb;
    }
    __syncthreads();
    unsigned short* xo = xnt + (size_t)b * (S_ * C_);
    #pragma unroll
    for (int i = 0; i < 4; i++) {
        int sr = tr + i * 16;
        ushort4 o4;
        o4.x = f2bf(tile[tc4 + 0][sr]);
        o4.y = f2bf(tile[tc4 + 1][sr]);
        o4.z = f2bf(tile[tc4 + 2][sr]);
        o4.w = f2bf(tile[tc4 + 3][sr]);
        *(ushort4*)(xo + (size_t)(s0 + sr) * C_ + c0 + tc4) = o4;
    }
}

// ================= 256x256 8-phase pipelined MFMA mainloop (BK=64) =================
// C[m][n] = sum_k A[m][k]*B[n][k], A/B bf16 K-contiguous. 8 waves (2M x 4N).
// LDS 128 KiB: per operand [buf2][khalf2][256 rows][32 ushort] (row stride 64 B).
// Swizzle: physical col-slot = logical ^ ((row>>1)&3)  (16B slots) -> conflict-free b128.
//   Applied on the GLOBAL source during staging (gl_lds dest is linear) and on ds_read.
// Per K-tile: 4 phases (kh, mhalf); each phase: ds_read (4 or 8 x b128) -> stage 1
// half-tile (2 x gl16) -> barrier -> lgkmcnt(0) -> setprio(1) 16 MFMA setprio(0) -> barrier.
// Stage schedule: ph0: A.k1[u+1], ph1: B.k1[u+1], ph2: A.k0[u+2], ph3: B.k0[u+2].
// Counted vmcnt(4) once per K-tile (retires tile u+1 in full, leaves u+2's k0 in flight);
// vmcnt(0) only at u==nt-2 (final drain). Requires nt >= 2.
template<bool SWAP>
__device__ __forceinline__ void mfma256_loop(const unsigned short* __restrict__ Ag, int lda,
                                             const unsigned short* __restrict__ Bg, int ldb,
                                             int nt, int m0, int n0,
                                             unsigned short* lds, floatx4 (&acc)[8][4]) {
    const int tid  = threadIdx.x;
    const int lane = tid & 63, wave = tid >> 6;
    const int wm = wave >> 2, wn = wave & 3;
    const int lrow = lane & 15, lq = lane >> 4;
    const int cs = lq ^ ((lrow >> 1) & 3);        // swizzled 16B col-slot for ds_read

    // ds_read offsets (ushort units) within one (buf,khalf) slab of 8 KiB
    int aofs[8], bofs[4];
    #pragma unroll
    for (int i = 0; i < 8; i++) aofs[i] = (wm * 128 + i * 16 + lrow) * 32 + cs * 8;
    #pragma unroll
    for (int j = 0; j < 4; j++) bofs[j] = (wn * 64 + j * 16 + lrow) * 32 + cs * 8;

    // staging: thread tid covers rows (tid>>2) and (tid>>2)+128, 16B slot (tid&3);
    // global col-slot pre-swizzled so linear LDS landing matches the swizzled read.
    const int sr  = tid >> 2;
    const int scs = (tid & 3) ^ ((tid >> 3) & 3);   // ((sr>>1)&3) xor; same for row sr+128
    const unsigned short* gA = Ag + (size_t)(m0 + sr) * lda + scs * 8;
    const unsigned short* gB = Bg + (size_t)(n0 + sr) * ldb + scs * 8;
    const size_t a128 = (size_t)128 * lda, b128 = (size_t)128 * ldb;
    unsigned short* lwA = lds + wave * 512;          // wave-uniform LDS bases
    unsigned short* lwB = lds + 32768 + wave * 512;

#define STAGE_A(t, kh) do { \
    unsigned short* lb_ = lwA + ((t) & 1) * 16384 + (kh) * 8192; \
    const unsigned short* gp_ = gA + (t) * 64 + (kh) * 32; \
    gl16(gp_, lb_); gl16(gp_ + a128, lb_ + 4096); } while (0)
#define STAGE_B(t, kh) do { \
    unsigned short* lb_ = lwB + ((t) & 1) * 16384 + (kh) * 8192; \
    const unsigned short* gp_ = gB + (t) * 64 + (kh) * 32; \
    gl16(gp_, lb_); gl16(gp_ + b128, lb_ + 4096); } while (0)

    // prologue: T0 fully + T1.k0 (12 loads); wait T0 (leave 4 in flight)
    STAGE_A(0, 0); STAGE_B(0, 0); STAGE_A(0, 1); STAGE_B(0, 1);
    STAGE_A(1, 0); STAGE_B(1, 0);
    asm volatile("s_waitcnt vmcnt(4)" ::: "memory");
    __builtin_amdgcn_s_barrier();

    bf16x8 af[4], bfr[4];
    for (int u = 0; u < nt; ++u) {
        const int p = u & 1;
        #pragma unroll
        for (int ph = 0; ph < 4; ++ph) {
            const int kh = ph >> 1, mh = ph & 1;
            const int slab = p * 16384 + kh * 8192;
            if (mh == 0) {                               // B frags reused across mhalves
                #pragma unroll
                for (int j = 0; j < 4; j++)
                    bfr[j] = *(const bf16x8*)(lds + 32768 + slab + bofs[j]);
            }
            #pragma unroll
            for (int i = 0; i < 4; i++)
                af[i] = *(const bf16x8*)(lds + slab + aofs[mh * 4 + i]);
            if (ph == 0)      { if (u + 1 < nt) STAGE_A(u + 1, 1); }
            else if (ph == 1) { if (u + 1 < nt) STAGE_B(u + 1, 1); }
            else if (ph == 2) { if (u + 2 < nt) STAGE_A(u + 2, 0); }
            else              { if (u + 2 < nt) STAGE_B(u + 2, 0); }
            __builtin_amdgcn_s_barrier();
            asm volatile("s_waitcnt lgkmcnt(0)" ::: "memory");
            __builtin_amdgcn_sched_barrier(0);
            __builtin_amdgcn_s_setprio(1);
            #pragma unroll
            for (int i = 0; i < 4; i++)
                #pragma unroll
                for (int j = 0; j < 4; j++) {
                    if (SWAP)
                        acc[mh * 4 + i][j] = __builtin_amdgcn_mfma_f32_16x16x32_bf16(
                            bfr[j], af[i], acc[mh * 4 + i][j], 0, 0, 0);
                    else
                        acc[mh * 4 + i][j] = __builtin_amdgcn_mfma_f32_16x16x32_bf16(
                            af[i], bfr[j], acc[mh * 4 + i][j], 0, 0, 0);
                }
            __builtin_amdgcn_s_setprio(0);
            if (ph < 3) {
                __builtin_amdgcn_s_barrier();
            } else if (u < nt - 2) {
                asm volatile("s_waitcnt vmcnt(4)" ::: "memory");  // tile u+1 fully landed
                __builtin_amdgcn_s_barrier();
            } else if (u == nt - 2) {
                asm volatile("s_waitcnt vmcnt(0)" ::: "memory");  // final drain
                __builtin_amdgcn_s_barrier();
            }   // u == nt-1: fall through to epilogue
        }
    }
#undef STAGE_A
#undef STAGE_B
}

#define GEMM256_PROLOGUE                                              \
    __shared__ __align__(16) unsigned short lds[65536];               \
    const int b = blockIdx.z;                                         \
    const int m0 = blockIdx.y * 256, n0 = blockIdx.x * 256;           \
    const int lane = threadIdx.x & 63, wave = threadIdx.x >> 6;       \
    const int wm = wave >> 2, wn = wave & 3;                          \
    const int lrow = lane & 15, lq = lane >> 4;                       \
    floatx4 acc[8][4];                                                \
    _Pragma("unroll") for (int i = 0; i < 8; i++)                     \
        _Pragma("unroll") for (int j = 0; j < 4; j++)                 \
            acc[i][j] = (floatx4){0.f, 0.f, 0.f, 0.f};

// ---------------- QKV projection ----------------
// A = wqkv_bf [1536][512], B = xnt[b] [1024][512].
// m-tiles 0-3 -> Q,K stored [s][c] (K pre-scaled by SCALE_), 4-5 -> V[c][s] (SWAP).
__global__ __launch_bounds__(512, 2) void qkv_mfma(const unsigned short* __restrict__ wbf,
                                                   const unsigned short* __restrict__ xnt,
                                                   const float* __restrict__ bias,
                                                   unsigned short* __restrict__ Qb,
                                                   unsigned short* __restrict__ Kb,
                                                   unsigned short* __restrict__ Vb) {
    GEMM256_PROLOGUE
    const unsigned short* Bg = xnt + (size_t)b * (S_ * C_);
    if (m0 < 1024) {
        mfma256_loop<false>(wbf, C_, Bg, C_, 8, m0, n0, lds, acc);
        unsigned short* dst = (m0 < 512 ? Qb : Kb) + (size_t)b * (S_ * C_);
        const int osec = (m0 < 512) ? 0 : 512;
        const float sc = (m0 < 512) ? 1.f : SCALE_;
        #pragma unroll
        for (int i = 0; i < 8; i++)
            #pragma unroll
            for (int j = 0; j < 4; j++) {
                int oabs = m0 + wm * 128 + i * 16 + lq * 4;
                int s    = n0 + wn * 64 + j * 16 + lrow;
                float4 bi = *(const float4*)(bias + oabs);
                floatx4 v = acc[i][j];
                ushort4 o4;
                o4.x = f2bf((v[0] + bi.x) * sc); o4.y = f2bf((v[1] + bi.y) * sc);
                o4.z = f2bf((v[2] + bi.z) * sc); o4.w = f2bf((v[3] + bi.w) * sc);
                *(ushort4*)(dst + (size_t)s * C_ + (oabs - osec)) = o4;
            }
    } else {
        mfma256_loop<true>(wbf, C_, Bg, C_, 8, m0, n0, lds, acc);
        unsigned short* dst = Vb + (size_t)b * (C_ * S_);
        #pragma unroll
        for (int i = 0; i < 8; i++)
            #pragma unroll
            for (int j = 0; j < 4; j++) {
                int c  = m0 - 1024 + wm * 128 + i * 16 + lrow;
                int sb = n0 + wn * 64 + j * 16 + lq * 4;
                float bi = bias[1024 + c];
                floatx4 v = acc[i][j];
                ushort4 o4;
                o4.x = f2bf(v[0] + bi); o4.y = f2bf(v[1] + bi);
                o4.z = f2bf(v[2] + bi); o4.w = f2bf(v[3] + bi);
                *(ushort4*)(dst + (size_t)c * S_ + sb) = o4;
            }
    }
}

// ---------------- scores: attn[i][j] = Q[i][:] . K[j][:] (scale already in K) ----------------
// SWAP => lane holds 4 consecutive j for fixed i -> ushort4 row store.
__global__ __launch_bounds__(512, 2) void scores_mfma(const unsigned short* __restrict__ Qb,
                                                      const unsigned short* __restrict__ Kb,
                                                      unsigned short* __restrict__ attn) {
    GEMM256_PROLOGUE
    const unsigned short* Ag = Qb + (size_t)b * (S_ * C_);
    const unsigned short* Bg = Kb + (size_t)b * (S_ * C_);
    mfma256_loop<true>(Ag, C_, Bg, C_, 8, m0, n0, lds, acc);
    unsigned short* ap = attn + (size_t)b * (S_ * S_);
    #pragma unroll
    for (int i = 0; i < 8; i++)
        #pragma unroll
        for (int j = 0; j < 4; j++) {
            int qi = m0 + wm * 128 + i * 16 + lrow;
            int jb = n0 + wn * 64 + j * 16 + lq * 4;
            floatx4 v = acc[i][j];
            ushort4 o4;
            o4.x = f2bf(v[0]); o4.y = f2bf(v[1]); o4.z = f2bf(v[2]); o4.w = f2bf(v[3]);
            *(ushort4*)(ap + (size_t)qi * S_ + jb) = o4;
        }
}

// ---------------- softmax rows (in place bf16) ----------------
__global__ __launch_bounds__(256) void softmax_rows(unsigned short* __restrict__ attn) {
    unsigned short* p = attn + (size_t)blockIdx.x * S_;
    const int t = threadIdx.x;
    ushort4 uv = *(const ushort4*)(p + t * 4);
    float v0 = bf2f(uv.x), v1 = bf2f(uv.y), v2 = bf2f(uv.z), v3 = bf2f(uv.w);
    float m = fmaxf(fmaxf(v0, v1), fmaxf(v2, v3));
    #pragma unroll
    for (int o = 32; o; o >>= 1) m = fmaxf(m, __shfl_down(m, o));
    __shared__ float lm[4], lsum[4];
    const int wid = t >> 6, lane = t & 63;
    if (lane == 0) lm[wid] = m;
    __syncthreads();
    m = fmaxf(fmaxf(lm[0], lm[1]), fmaxf(lm[2], lm[3]));
    float e0 = __expf(v0 - m), e1 = __expf(v1 - m), e2 = __expf(v2 - m), e3 = __expf(v3 - m);
    float s = e0 + e1 + e2 + e3;
    #pragma unroll
    for (int o = 32; o; o >>= 1) s += __shfl_down(s, o);
    if (lane == 0) lsum[wid] = s;
    __syncthreads();
    float T = lsum[0] + lsum[1] + lsum[2] + lsum[3];
    float r = __frcp_rn(T);
    ushort4 ov;
    ov.x = f2bf(e0 * r); ov.y = f2bf(e1 * r); ov.z = f2bf(e2 * r); ov.w = f2bf(e3 * r);
    *(ushort4*)(p + t * 4) = ov;
}

// ---------------- PV: O[i][c] = sum_j P[i][j] V[c][j] ----------------
// SWAP => lane holds 4 consecutive c for fixed i -> ushort4 row store.
__global__ __launch_bounds__(512, 2) void pv_mfma(const unsigned short* __restrict__ attn,
                                                  const unsigned short* __restrict__ Vb,
                                                  unsigned short* __restrict__ Ob) {
    GEMM256_PROLOGUE
    const unsigned short* Ag = attn + (size_t)b * (S_ * S_);
    const unsigned short* Bg = Vb + (size_t)b * (C_ * S_);
    mfma256_loop<true>(Ag, S_, Bg, S_, 16, m0, n0, lds, acc);
    unsigned short* op = Ob + (size_t)b * (S_ * C_);
    #pragma unroll
    for (int i = 0; i < 8; i++)
        #pragma unroll
        for (int j = 0; j < 4; j++) {
            int qi = m0 + wm * 128 + i * 16 + lrow;
            int cb = n0 + wn * 64 + j * 16 + lq * 4;
            floatx4 v = acc[i][j];
            ushort4 o4;
            o4.x = f2bf(v[0]); o4.y = f2bf(v[1]); o4.z = f2bf(v[2]); o4.w = f2bf(v[3]);
            *(ushort4*)(op + (size_t)qi * C_ + cb) = o4;
        }
}

// ---------------- out projection + bias + residual ----------------
// SWAP => lane holds 4 consecutive s for fixed o -> float4 store + float4 residual load.
__global__ __launch_bounds__(512, 2) void out_mfma(const unsigned short* __restrict__ wbf,
                                                   const unsigned short* __restrict__ Ob,
                                                   const float* __restrict__ bias,
                                                   const float* __restrict__ x,
                                                   float* __restrict__ out) {
    GEMM256_PROLOGUE
    const unsigned short* Bg = Ob + (size_t)b * (S_ * C_);
    mfma256_loop<true>(wbf, C_, Bg, C_, 8, m0, n0, lds, acc);
    const float* xb = x + (size_t)b * (C_ * S_);
    float* ob = out + (size_t)b * (C_ * S_);
    #pragma unroll
    for (int i = 0; i < 8; i++)
        #pragma unroll
        for (int j = 0; j < 4; j++) {
            int o  = m0 + wm * 128 + i * 16 + lrow;
            int sb = n0 + wn * 64 + j * 16 + lq * 4;
            float bb = bias[o];
            size_t idx = (size_t)o * S_ + sb;
            float4 xv = *(const float4*)(xb + idx);
            floatx4 v = acc[i][j];
            float4 r;
            r.x = v[0] + bb + xv.x; r.y = v[1] + bb + xv.y;
            r.z = v[2] + bb + xv.z; r.w = v[3] + bb + xv.w;
            *(float4*)(ob + idx) = r;
        }
}

// ---------------- launch ----------------
extern "C" void kernel_launch(void* const* d_in, const int* in_sizes, int n_in,
                              void* d_out, int out_size, void* d_ws, size_t ws_size,
                              hipStream_t stream) {
    const float* x      = (const float*)d_in[0];
    const float* gamma  = (const float*)d_in[1];
    const float* beta   = (const float*)d_in[2];
    const float* w_qkv  = (const float*)d_in[3];
    const float* b_qkv  = (const float*)d_in[4];
    const float* w_out  = (const float*)d_in[5];
    const float* b_out  = (const float*)d_in[6];
    float* out          = (float*)d_out;

    char* ws = (char*)d_ws;
    // layout (bytes), aliasing is stream-order safe:
    //   Qb   [b][1024][512] bf16 @ 0         (32 MB)  -- dead after scores
    //   Kb   [b][1024][512] bf16 @ 32 MB     (32 MB)
    //   Vb   [b][512][1024] bf16 @ 64 MB     (32 MB)
    //   xnt  [b][1024][512] bf16 @ 96 MB     (32 MB)  -- dead after qkv
    //   attn [b][1024][1024] bf16 @ 96 MB    (64 MB)  -- aliases xnt
    //   Ob   [b][1024][512] bf16 @ 0         (32 MB)  -- aliases Qb
    //   wqkv_bf @ 160 MB, wout_bf, stats     (~2.1 MB)
    unsigned short* Qb   = (unsigned short*)(ws);
    unsigned short* Kb   = (unsigned short*)(ws + 33554432ULL);
    unsigned short* Vb   = (unsigned short*)(ws + 67108864ULL);
    unsigned short* xnt  = (unsigned short*)(ws + 100663296ULL);
    unsigned short* attn = (unsigned short*)(ws + 100663296ULL);
    unsigned short* Ob   = (unsigned short*)(ws);
    unsigned short* wqkv_bf = (unsigned short*)(ws + 167772160ULL);
    unsigned short* wout_bf = (unsigned short*)(ws + 167772160ULL + 1572864ULL);
    float2* stats           = (float2*)(ws + 167772160ULL + 1572864ULL + 524288ULL);

    gn_stats  <<<B_ * G_, 256, 0, stream>>>(x, stats);
    cast_bf16 <<<C3_ * C_ / 1024, 256, 0, stream>>>(w_qkv, wqkv_bf);
    cast_bf16 <<<C_ * C_ / 1024, 256, 0, stream>>>(w_out, wout_bf);
    xnt_kernel<<<dim3(16, 8, B_), 256, 0, stream>>>(x, gamma, beta, stats, xnt);
    qkv_mfma  <<<dim3(4, 6, B_), 512, 0, stream>>>(wqkv_bf, xnt, b_qkv, Qb, Kb, Vb);
    scores_mfma<<<dim3(4, 4, B_), 512, 0, stream>>>(Qb, Kb, attn);
    softmax_rows<<<B_ * S_, 256, 0, stream>>>(attn);
    pv_mfma   <<<dim3(2, 4, B_), 512, 0, stream>>>(attn, Vb, Ob);
    out_mfma  <<<dim3(4, 2, B_), 512, 0, stream>>>(wout_bf, Ob, b_out, x, out);
}